// Round 4
// baseline (173.117 us; speedup 1.0000x reference)
//
#include <hip/hip_runtime.h>

#define PP 256
#define SS 256
#define CORE_ 192
#define HH 256
#define NHEAD 8
#define DD 32

typedef __attribute__((ext_vector_type(4))) float f32x4;
typedef __attribute__((ext_vector_type(8))) short s8v;
typedef __attribute__((ext_vector_type(4))) short s4v;

__device__ __forceinline__ float bf2f(unsigned short u) {
    union { unsigned int i; float f; } c; c.i = ((unsigned int)u) << 16; return c.f;
}
__device__ __forceinline__ unsigned short f2bf(float f) {
    union { float f; unsigned int i; } c; c.f = f;
    unsigned int i = c.i;
    return (unsigned short)((i + 0x7fffu + ((i >> 16) & 1u)) >> 16);
}

// 16B-chunk XOR swizzle for [rows][32-short] LDS tiles (4 chunks/row). 0-conflict measured.
#define SW(row, chunk) ((chunk) ^ (((row) >> 1) & 3))
// swizzle for the resident A tile [64][256]: 32 slots of 16B per row
#define ASW(row, s) ((s) ^ ((row) & 7) ^ (((s) >> 3) & 7))

// ---------------- K0: weight/bias pack (f32 -> bf16, once) -------------
// blocks 0..255: Wb rows (Wq 0-255 | Wk 256-511 | Wv 512-767 | Wo 768-1023)
// blocks 256..258: bb[768] = {bq, bk, bv}
__global__ __launch_bounds__(256) void k_prep(
    const float* __restrict__ Wq, const float* __restrict__ Wk,
    const float* __restrict__ Wv, const float* __restrict__ Wo,
    const float* __restrict__ bq, const float* __restrict__ bk,
    const float* __restrict__ bv,
    unsigned short* __restrict__ Wb, float* __restrict__ bb) {
    int bid = blockIdx.x, tid = threadIdx.x;
    if (bid >= 256) {
        int which = bid - 256;
        const float* b = which == 0 ? bq : which == 1 ? bk : bv;
        bb[which * 256 + tid] = b[tid];
        return;
    }
    int i = bid * 256 + tid;        // one float4 each
    int row = i >> 6;               // 0..1023
    int col4 = (i & 63) * 4;
    const float* src = row < 256 ? Wq : row < 512 ? Wk : row < 768 ? Wv : Wo;
    float4 v = *(const float4*)(src + (size_t)(row & 255) * 256 + col4);
    s4v w;
    w[0] = (short)f2bf(v.x); w[1] = (short)f2bf(v.y);
    w[2] = (short)f2bf(v.z); w[3] = (short)f2bf(v.w);
    *(s4v*)(Wb + (size_t)row * 256 + col4) = w;
}

// ---------------- K1: QKV projection (merged Q,K,V) --------------------
// grid (P, 4 mt of 64 rows), block 256 (4 waves).
// A (gathered x, bf16) resident in LDS; N=768 in 4 quarters of 192 cols;
// per k-step: stage Bs[192][32] (pure bf16 copy) -> 12 MFMA per wave.
__global__ __launch_bounds__(256) void k_qkv(
    const float* __restrict__ x, const int* __restrict__ pidx,
    const unsigned short* __restrict__ Wb, const float* __restrict__ bb,
    unsigned short* __restrict__ qkv) {
    int p = blockIdx.x, mt = blockIdx.y;
    __shared__ unsigned short As[64][256];
    __shared__ unsigned short Bs[192][32];
    int tid = threadIdx.x;
    int wave = tid >> 6, lane = tid & 63;
    int g = lane >> 4, c0 = lane & 15;

    // ---- stage A once: gather + convert, swizzled ----
    {
        int row = tid >> 2;
        int sb = (tid & 3) * 8;
        int node = pidx[p * SS + mt * 64 + row];
        const float* src = x + (size_t)node * HH;
#pragma unroll
        for (int i = 0; i < 8; ++i) {
            int s = sb + i;
            float4 a = *(const float4*)(src + s * 8);
            float4 b = *(const float4*)(src + s * 8 + 4);
            s8v w;
            w[0] = (short)f2bf(a.x); w[1] = (short)f2bf(a.y);
            w[2] = (short)f2bf(a.z); w[3] = (short)f2bf(a.w);
            w[4] = (short)f2bf(b.x); w[5] = (short)f2bf(b.y);
            w[6] = (short)f2bf(b.z); w[7] = (short)f2bf(b.w);
            *(s8v*)&As[row][ASW(row, s) * 8] = w;
        }
    }
    __syncthreads();

    for (int q = 0; q < 4; ++q) {
        if (mt == 3 && q == 0) continue;  // Q rows 192..255 never consumed
        f32x4 acc[4][3] = {};
        for (int ks = 0; ks < 8; ++ks) {
            // stage B: output-cols q*192..q*192+191, k-slice ks*32..+32
#pragma unroll
            for (int j = 0; j < 3; ++j) {
                int task = tid + 256 * j;       // 0..767
                int nr = task >> 2, sl = task & 3;
                s8v w = *(const s8v*)(Wb + (size_t)(q * 192 + nr) * 256 + ks * 32 + sl * 8);
                *(s8v*)&Bs[nr][SW(nr, sl) * 8] = w;
            }
            __syncthreads();
            s8v af[4];
#pragma unroll
            for (int m2 = 0; m2 < 4; ++m2) {
                int r = m2 * 16 + c0;
                af[m2] = *(const s8v*)&As[r][ASW(r, ks * 4 + g) * 8];
            }
#pragma unroll
            for (int nt = 0; nt < 3; ++nt) {
                int T = q * 12 + wave * 3 + nt;
                if (mt == 3 && T < 16) continue;  // Q tiles for skipped rows
                int nr = (wave * 3 + nt) * 16 + c0;
                s8v bf = *(const s8v*)&Bs[nr][SW(nr, g) * 8];
#pragma unroll
                for (int m2 = 0; m2 < 4; ++m2)
                    acc[m2][nt] = __builtin_amdgcn_mfma_f32_16x16x32_bf16(
                        af[m2], bf, acc[m2][nt], 0, 0, 0);
            }
            __syncthreads();
        }
        // store quarter (+bias)
#pragma unroll
        for (int nt = 0; nt < 3; ++nt) {
            int T = q * 12 + wave * 3 + nt;
            if (mt == 3 && T < 16) continue;
            int col = T * 16 + c0;
            float bv_ = bb[col];
#pragma unroll
            for (int m2 = 0; m2 < 4; ++m2)
#pragma unroll
                for (int r = 0; r < 4; ++r) {
                    int srow = mt * 64 + m2 * 16 + g * 4 + r;
                    qkv[((size_t)p * SS + srow) * 768 + col] =
                        f2bf(acc[m2][nt][r] + bv_);
                }
        }
    }
}

// ---------------- K2: attention (MFMA) ---------------------------------
// grid (P, HEADS), block 256 = 4 waves; wave w handles mtiles w*3..w*3+2.
__global__ __launch_bounds__(256) void k_attn(
    const unsigned short* __restrict__ qkv, unsigned short* __restrict__ att) {
    int p = blockIdx.x, h = blockIdx.y;
    __shared__ unsigned short Ks[256][32];
    __shared__ unsigned short Vt[32][256];
    __shared__ unsigned short Pb[4][16][256];
    int tid = threadIdx.x;
    int wave = tid >> 6, lane = tid & 63;
    int g = lane >> 4, c0 = lane & 15;

    {
        int chunk = tid & 3, rb = tid >> 2;
#pragma unroll
        for (int pass = 0; pass < 4; ++pass) {
            int row = rb + pass * 64;
            const unsigned short* kb =
                qkv + ((size_t)p * SS + row) * 768 + 256 + h * DD + chunk * 8;
            s8v kv = *(const s8v*)kb;
            s8v vv = *(const s8v*)(kb + 256);
            *(s8v*)&Ks[row][SW(row, chunk) * 8] = kv;
            int cj = row >> 3, jo = row & 7;
#pragma unroll
            for (int e = 0; e < 8; ++e) {
                int d = chunk * 8 + e;
                Vt[d][((cj ^ ((d >> 1) & 7)) << 3) + jo] = (unsigned short)vv[e];
            }
        }
    }
    __syncthreads();

    const float scale = 0.17677669529663687f;  // 1/sqrt(32)
    int cs = (c0 >> 1) & 7;

    for (int mi = 0; mi < 3; ++mi) {
        int q0 = (wave * 3 + mi) * 16;
        s8v qa = *(const s8v*)(qkv + ((size_t)p * SS + q0 + c0) * 768 + h * DD + g * 8);
        f32x4 sacc[16];
#pragma unroll
        for (int jt = 0; jt < 16; ++jt) {
            int row = jt * 16 + c0;
            s8v kf = *(const s8v*)&Ks[row][SW(row, g) * 8];
            sacc[jt] = __builtin_amdgcn_mfma_f32_16x16x32_bf16(
                qa, kf, f32x4{0.f, 0.f, 0.f, 0.f}, 0, 0, 0);
        }
        float linv[4];
#pragma unroll
        for (int r = 0; r < 4; ++r) {
            float mx = sacc[0][r];
#pragma unroll
            for (int jt = 1; jt < 16; ++jt) mx = fmaxf(mx, sacc[jt][r]);
#pragma unroll
            for (int off = 1; off < 16; off <<= 1)
                mx = fmaxf(mx, __shfl_xor(mx, off, 64));
            float sum = 0.f;
#pragma unroll
            for (int jt = 0; jt < 16; ++jt) {
                float e = __expf((sacc[jt][r] - mx) * scale);
                sacc[jt][r] = e;
                sum += e;
            }
#pragma unroll
            for (int off = 1; off < 16; off <<= 1)
                sum += __shfl_xor(sum, off, 64);
            linv[r] = 1.f / sum;
            int qq = g * 4 + r;
            int qs = (qq >> 1) & 7;
            unsigned short* prow = &Pb[wave][qq][0];
#pragma unroll
            for (int jt = 0; jt < 16; ++jt) {
                int j0 = jt * 2 + (c0 >> 3);
                prow[((j0 ^ qs) << 3) + (c0 & 7)] = (unsigned short)f2bf(sacc[jt][r]);
            }
        }
        asm volatile("s_waitcnt lgkmcnt(0)" ::: "memory");
        __builtin_amdgcn_sched_barrier(0);
        f32x4 oacc[2] = {f32x4{0.f, 0.f, 0.f, 0.f}, f32x4{0.f, 0.f, 0.f, 0.f}};
#pragma unroll
        for (int kt = 0; kt < 8; ++kt) {
            s8v pa = *(const s8v*)&Pb[wave][c0][(((kt * 4 + g) ^ cs) << 3)];
#pragma unroll
            for (int nt = 0; nt < 2; ++nt) {
                int d = nt * 16 + c0;
                s8v vb = *(const s8v*)&Vt[d][(((kt * 4 + g) ^ ((d >> 1) & 7)) << 3)];
                oacc[nt] = __builtin_amdgcn_mfma_f32_16x16x32_bf16(
                    pa, vb, oacc[nt], 0, 0, 0);
            }
        }
        asm volatile("s_waitcnt lgkmcnt(0)" ::: "memory");
        __builtin_amdgcn_sched_barrier(0);
#pragma unroll
        for (int nt = 0; nt < 2; ++nt)
#pragma unroll
            for (int r = 0; r < 4; ++r) {
                int qq = g * 4 + r;
                att[((size_t)p * CORE_ + q0 + qq) * HH + h * DD + nt * 16 + c0] =
                    f2bf(oacc[nt][r] * linv[r]);
            }
    }
}

// ---------------- K3: out-proj + residual + LayerNorm ------------------
__global__ __launch_bounds__(256) void k_out(
    const unsigned short* __restrict__ att, const float* __restrict__ x,
    const unsigned short* __restrict__ Wb, const float* __restrict__ bo,
    const float* __restrict__ ln_g, const float* __restrict__ ln_b,
    float* __restrict__ out) {
    int p = blockIdx.x, mb = blockIdx.y;
    __shared__ unsigned short As[64][32];
    __shared__ unsigned short Bs[256][32];
    int tid = threadIdx.x;
    int wave = tid >> 6, lane = tid & 63;
    int g = lane >> 4, c0 = lane & 15;
    f32x4 acc[16] = {};
    int arow = tid >> 2, aseg = tid & 3;
    const unsigned short* asrc =
        att + ((size_t)p * CORE_ + mb * 64 + arow) * HH + aseg * 8;

    for (int k0 = 0; k0 < HH; k0 += 32) {
        *(s8v*)&As[arow][SW(arow, aseg) * 8] = *(const s8v*)(asrc + k0);
#pragma unroll
        for (int j = 0; j < 4; ++j) {
            int task = tid + 256 * j;       // 0..1023
            int nr = task >> 2, sl = task & 3;
            s8v w = *(const s8v*)(Wb + (size_t)(768 + nr) * 256 + k0 + sl * 8);
            *(s8v*)&Bs[nr][SW(nr, sl) * 8] = w;
        }
        __syncthreads();
        int ar = wave * 16 + c0;
        s8v af = *(const s8v*)&As[ar][SW(ar, g) * 8];
#pragma unroll
        for (int nt = 0; nt < 16; ++nt) {
            int r = nt * 16 + c0;
            s8v bfv = *(const s8v*)&Bs[r][SW(r, g) * 8];
            acc[nt] = __builtin_amdgcn_mfma_f32_16x16x32_bf16(af, bfv, acc[nt], 0, 0, 0);
        }
        __syncthreads();
    }
    int srow0 = mb * 64 + wave * 16 + g * 4;
    float sum[4] = {0, 0, 0, 0}, ssq[4] = {0, 0, 0, 0};
#pragma unroll
    for (int nt = 0; nt < 16; ++nt) {
        int col = nt * 16 + c0;
        float bov = bo[col];
#pragma unroll
        for (int r = 0; r < 4; ++r) {
            size_t node = (size_t)p * CORE_ + srow0 + r;
            float v = acc[nt][r] + bov + x[node * HH + col];
            acc[nt][r] = v;
            sum[r] += v; ssq[r] += v * v;
        }
    }
#pragma unroll
    for (int off = 1; off < 16; off <<= 1) {
#pragma unroll
        for (int r = 0; r < 4; ++r) {
            sum[r] += __shfl_xor(sum[r], off, 64);
            ssq[r] += __shfl_xor(ssq[r], off, 64);
        }
    }
#pragma unroll
    for (int r = 0; r < 4; ++r) {
        float mu = sum[r] * (1.f / HH);
        float var = ssq[r] * (1.f / HH) - mu * mu;
        float rstd = rsqrtf(var + 1e-5f);
        size_t node = (size_t)p * CORE_ + srow0 + r;
#pragma unroll
        for (int nt = 0; nt < 16; ++nt) {
            int col = nt * 16 + c0;
            out[node * HH + col] = (acc[nt][r] - mu) * rstd * ln_g[col] + ln_b[col];
        }
    }
}

extern "C" void kernel_launch(void* const* d_in, const int* in_sizes, int n_in,
                              void* d_out, int out_size, void* d_ws, size_t ws_size,
                              hipStream_t stream) {
    const float* x   = (const float*)d_in[0];
    const int* pidx  = (const int*)d_in[1];
    const float* Wq  = (const float*)d_in[3];
    const float* bq  = (const float*)d_in[4];
    const float* Wk  = (const float*)d_in[5];
    const float* bk  = (const float*)d_in[6];
    const float* Wv  = (const float*)d_in[7];
    const float* bv  = (const float*)d_in[8];
    const float* Wo  = (const float*)d_in[9];
    const float* bo  = (const float*)d_in[10];
    const float* lng = (const float*)d_in[11];
    const float* lnb = (const float*)d_in[12];

    // ws: qkv bf16 [P][S][768] (100.7MB) | att bf16 [P][192][256] (25.2MB)
    //     | Wb bf16 [1024][256] (0.5MB) | bb f32 [768]
    unsigned short* qkv = (unsigned short*)d_ws;
    unsigned short* att = qkv + (size_t)PP * SS * 768;
    unsigned short* Wb  = att + (size_t)PP * CORE_ * HH;
    float* bb = (float*)(Wb + 1024 * 256);

    k_prep<<<259, 256, 0, stream>>>(Wq, Wk, Wv, Wo, bq, bk, bv, Wb, bb);
    k_qkv<<<dim3(PP, 4), 256, 0, stream>>>(x, pidx, Wb, bb, qkv);
    k_attn<<<dim3(PP, NHEAD), 256, 0, stream>>>(qkv, att);
    k_out<<<dim3(PP, 3), 256, 0, stream>>>(att, x, Wb, bo, lng, lnb, (float*)d_out);
}

// Round 5
// 166.864 us; speedup vs baseline: 1.0375x; 1.0375x over previous
//
#include <hip/hip_runtime.h>

#define PP 256
#define SS 256
#define CORE_ 192
#define HH 256
#define NHEAD 8
#define DD 32

typedef __attribute__((ext_vector_type(4))) float f32x4;
typedef __attribute__((ext_vector_type(8))) short s8v;
typedef __attribute__((ext_vector_type(4))) short s4v;

__device__ __forceinline__ float bf2f(unsigned short u) {
    union { unsigned int i; float f; } c; c.i = ((unsigned int)u) << 16; return c.f;
}
__device__ __forceinline__ unsigned short f2bf(float f) {
    union { float f; unsigned int i; } c; c.f = f;
    unsigned int i = c.i;
    return (unsigned short)((i + 0x7fffu + ((i >> 16) & 1u)) >> 16);
}

// async global->LDS 16B DMA; lds base must be wave-uniform (HW adds lane*16)
__device__ __forceinline__ void gload16(const unsigned short* g, unsigned short* l) {
    __builtin_amdgcn_global_load_lds(
        (const __attribute__((address_space(1))) void*)g,
        (__attribute__((address_space(3))) void*)l, 16, 0, 0);
}

// 16B-chunk XOR swizzle for reg-staged [rows][32-short] LDS tiles (0-conflict measured r3)
#define SW(row, chunk) ((chunk) ^ (((row) >> 1) & 3))

// ---------------- K0: weight/bias pack (f32 -> bf16, once) -------------
// blocks 0..255: Wb rows (Wq 0-255 | Wk 256-511 | Wv 512-767 | Wo 768-1023)
// blocks 256..258: bb[768] = {bq, bk, bv}
__global__ __launch_bounds__(256) void k_prep(
    const float* __restrict__ Wq, const float* __restrict__ Wk,
    const float* __restrict__ Wv, const float* __restrict__ Wo,
    const float* __restrict__ bq, const float* __restrict__ bk,
    const float* __restrict__ bv,
    unsigned short* __restrict__ Wb, float* __restrict__ bb) {
    int bid = blockIdx.x, tid = threadIdx.x;
    if (bid >= 256) {
        int which = bid - 256;
        const float* b = which == 0 ? bq : which == 1 ? bk : bv;
        bb[which * 256 + tid] = b[tid];
        return;
    }
    int i = bid * 256 + tid;        // one float4 each
    int row = i >> 6;               // 0..1023
    int col4 = (i & 63) * 4;
    const float* src = row < 256 ? Wq : row < 512 ? Wk : row < 768 ? Wv : Wo;
    float4 v = *(const float4*)(src + (size_t)(row & 255) * 256 + col4);
    s4v w;
    w[0] = (short)f2bf(v.x); w[1] = (short)f2bf(v.y);
    w[2] = (short)f2bf(v.z); w[3] = (short)f2bf(v.w);
    *(s4v*)(Wb + (size_t)row * 256 + col4) = w;
}

// ---------------- K1: QKV projection -----------------------------------
// grid (P, 4 mt of 64 rows, 3 {Q,K,V}), block 256 (4 waves). Round-3 structure:
// 8 k-steps; A reg-staged (gather f32 -> bf16, SW layout); B via global_load_lds
// from packed Wb (linear LDS, zero VALU).
__global__ __launch_bounds__(256) void k_qkv(
    const float* __restrict__ x, const int* __restrict__ pidx,
    const unsigned short* __restrict__ Wb, const float* __restrict__ bb,
    unsigned short* __restrict__ qkv) {
    int p = blockIdx.x, mt = blockIdx.y, ng = blockIdx.z;
    if (ng == 0 && mt == 3) return;  // Q rows 192..255 never consumed
    __shared__ unsigned short As[64][32];
    __shared__ unsigned short Bs[256][32];
    int tid = threadIdx.x;
    int wave = tid >> 6, lane = tid & 63;
    int g = lane >> 4, c0 = lane & 15;
    f32x4 acc[4][4] = {};
    int arow = tid >> 2, aseg = tid & 3;
    int node = pidx[p * SS + mt * 64 + arow];
    const float* asrc = x + (size_t)node * HH + aseg * 8;
    const unsigned short* wsrc = Wb + (size_t)ng * 256 * 256;

    for (int k0 = 0; k0 < HH; k0 += 32) {
        // ---- stage B: 256 rows x 32 shorts = 1024 x 16B chunks, async DMA ----
#pragma unroll
        for (int j = 0; j < 4; ++j) {
            int chunk = j * 256 + wave * 64 + lane;
            int row = chunk >> 2, c8 = chunk & 3;
            gload16(wsrc + (size_t)row * 256 + k0 + c8 * 8,
                    &Bs[0][0] + (size_t)(j * 256 + wave * 64) * 8);
        }
        // ---- stage A: gathered x rows -> bf16, SW-swizzled ----
        float4 v0 = *(const float4*)(asrc + k0);
        float4 v1 = *(const float4*)(asrc + k0 + 4);
        s8v aw;
        aw[0] = (short)f2bf(v0.x); aw[1] = (short)f2bf(v0.y);
        aw[2] = (short)f2bf(v0.z); aw[3] = (short)f2bf(v0.w);
        aw[4] = (short)f2bf(v1.x); aw[5] = (short)f2bf(v1.y);
        aw[6] = (short)f2bf(v1.z); aw[7] = (short)f2bf(v1.w);
        *(s8v*)&As[arow][SW(arow, aseg) * 8] = aw;
        __syncthreads();   // drains vmcnt+lgkmcnt
        s8v af[4], bfv[4];
#pragma unroll
        for (int m2 = 0; m2 < 4; ++m2) {
            int r = m2 * 16 + c0;
            af[m2] = *(const s8v*)&As[r][SW(r, g) * 8];
        }
#pragma unroll
        for (int nt = 0; nt < 4; ++nt) {
            int r = wave * 64 + nt * 16 + c0;
            bfv[nt] = *(const s8v*)&Bs[r][g * 8];
        }
#pragma unroll
        for (int m2 = 0; m2 < 4; ++m2)
#pragma unroll
            for (int nt = 0; nt < 4; ++nt)
                acc[m2][nt] = __builtin_amdgcn_mfma_f32_16x16x32_bf16(
                    af[m2], bfv[nt], acc[m2][nt], 0, 0, 0);
        __syncthreads();
    }
#pragma unroll
    for (int nt = 0; nt < 4; ++nt) {
        int ncol = wave * 64 + nt * 16 + c0;
        float bv_ = bb[ng * 256 + ncol];
#pragma unroll
        for (int m2 = 0; m2 < 4; ++m2)
#pragma unroll
            for (int r = 0; r < 4; ++r) {
                int srow = mt * 64 + m2 * 16 + g * 4 + r;
                qkv[((size_t)p * SS + srow) * 768 + ng * 256 + ncol] =
                    f2bf(acc[m2][nt][r] + bv_);
            }
    }
}

// ---------------- K2: attention (MFMA) ---------------------------------
// grid (P, HEADS), block 256 = 4 waves; wave w handles mtiles w*3..w*3+2.
// K staged via global_load_lds (linear); V reg-staged transposed (swizzled).
__global__ __launch_bounds__(256) void k_attn(
    const unsigned short* __restrict__ qkv, unsigned short* __restrict__ att) {
    int p = blockIdx.x, h = blockIdx.y;
    __shared__ unsigned short Ks[256][32];
    __shared__ unsigned short Vt[32][256];
    __shared__ unsigned short Pb[4][16][256];
    int tid = threadIdx.x;
    int wave = tid >> 6, lane = tid & 63;
    int g = lane >> 4, c0 = lane & 15;

    // ---- stage K (DMA, linear) ----
#pragma unroll
    for (int j = 0; j < 4; ++j) {
        int chunk = j * 256 + wave * 64 + lane;
        int row = chunk >> 2, c8 = chunk & 3;
        gload16(qkv + ((size_t)p * SS + row) * 768 + 256 + h * DD + c8 * 8,
                &Ks[0][0] + (size_t)(j * 256 + wave * 64) * 8);
    }
    // ---- stage V transposed (reg), swizzled ----
    {
        int chunk = tid & 3, rb = tid >> 2;
#pragma unroll
        for (int pass = 0; pass < 4; ++pass) {
            int row = rb + pass * 64;
            s8v vv = *(const s8v*)(qkv + ((size_t)p * SS + row) * 768 + 512 + h * DD + chunk * 8);
            int cj = row >> 3, jo = row & 7;
#pragma unroll
            for (int e = 0; e < 8; ++e) {
                int d = chunk * 8 + e;
                Vt[d][((cj ^ ((d >> 1) & 7)) << 3) + jo] = (unsigned short)vv[e];
            }
        }
    }
    __syncthreads();

    const float scale = 0.17677669529663687f;  // 1/sqrt(32)
    int cs = (c0 >> 1) & 7;

    for (int mi = 0; mi < 3; ++mi) {
        int q0 = (wave * 3 + mi) * 16;
        s8v qa = *(const s8v*)(qkv + ((size_t)p * SS + q0 + c0) * 768 + h * DD + g * 8);
        f32x4 sacc[16];
#pragma unroll
        for (int jt = 0; jt < 16; ++jt) {
            int row = jt * 16 + c0;
            s8v kf = *(const s8v*)&Ks[row][g * 8];
            sacc[jt] = __builtin_amdgcn_mfma_f32_16x16x32_bf16(
                qa, kf, f32x4{0.f, 0.f, 0.f, 0.f}, 0, 0, 0);
        }
        float linv[4];
#pragma unroll
        for (int r = 0; r < 4; ++r) {
            float mx = sacc[0][r];
#pragma unroll
            for (int jt = 1; jt < 16; ++jt) mx = fmaxf(mx, sacc[jt][r]);
#pragma unroll
            for (int off = 1; off < 16; off <<= 1)
                mx = fmaxf(mx, __shfl_xor(mx, off, 64));
            float sum = 0.f;
#pragma unroll
            for (int jt = 0; jt < 16; ++jt) {
                float e = __expf((sacc[jt][r] - mx) * scale);
                sacc[jt][r] = e;
                sum += e;
            }
#pragma unroll
            for (int off = 1; off < 16; off <<= 1)
                sum += __shfl_xor(sum, off, 64);
            linv[r] = 1.f / sum;
            int qq = g * 4 + r;
            int qs = (qq >> 1) & 7;
            unsigned short* prow = &Pb[wave][qq][0];
#pragma unroll
            for (int jt = 0; jt < 16; ++jt) {
                int j0 = jt * 2 + (c0 >> 3);
                prow[((j0 ^ qs) << 3) + (c0 & 7)] = (unsigned short)f2bf(sacc[jt][r]);
            }
        }
        asm volatile("s_waitcnt lgkmcnt(0)" ::: "memory");
        __builtin_amdgcn_sched_barrier(0);
        f32x4 oacc[2] = {f32x4{0.f, 0.f, 0.f, 0.f}, f32x4{0.f, 0.f, 0.f, 0.f}};
#pragma unroll
        for (int kt = 0; kt < 8; ++kt) {
            s8v pa = *(const s8v*)&Pb[wave][c0][(((kt * 4 + g) ^ cs) << 3)];
#pragma unroll
            for (int nt = 0; nt < 2; ++nt) {
                int d = nt * 16 + c0;
                s8v vb = *(const s8v*)&Vt[d][(((kt * 4 + g) ^ ((d >> 1) & 7)) << 3)];
                oacc[nt] = __builtin_amdgcn_mfma_f32_16x16x32_bf16(
                    pa, vb, oacc[nt], 0, 0, 0);
            }
        }
        asm volatile("s_waitcnt lgkmcnt(0)" ::: "memory");
        __builtin_amdgcn_sched_barrier(0);
#pragma unroll
        for (int nt = 0; nt < 2; ++nt)
#pragma unroll
            for (int r = 0; r < 4; ++r) {
                int qq = g * 4 + r;
                att[((size_t)p * CORE_ + q0 + qq) * HH + h * DD + nt * 16 + c0] =
                    f2bf(oacc[nt][r] * linv[r]);
            }
    }
}

// ---------------- K3: out-proj + residual + LayerNorm ------------------
// A (att) and B (Wo from Wb) both staged via global_load_lds, linear LDS.
__global__ __launch_bounds__(256) void k_out(
    const unsigned short* __restrict__ att, const float* __restrict__ x,
    const unsigned short* __restrict__ Wb, const float* __restrict__ bo,
    const float* __restrict__ ln_g, const float* __restrict__ ln_b,
    float* __restrict__ out) {
    int p = blockIdx.x, mb = blockIdx.y;
    __shared__ unsigned short As[64][32];
    __shared__ unsigned short Bs[256][32];
    int tid = threadIdx.x;
    int wave = tid >> 6, lane = tid & 63;
    int g = lane >> 4, c0 = lane & 15;
    f32x4 acc[16] = {};

    for (int k0 = 0; k0 < HH; k0 += 32) {
        // A: 64 rows x 32 shorts = 256 chunks
        {
            int chunk = wave * 64 + lane;
            int row = chunk >> 2, c8 = chunk & 3;
            gload16(att + ((size_t)p * CORE_ + mb * 64 + row) * HH + k0 + c8 * 8,
                    &As[0][0] + (size_t)(wave * 64) * 8);
        }
        // B: Wo rows (Wb 768..1023), 1024 chunks
#pragma unroll
        for (int j = 0; j < 4; ++j) {
            int chunk = j * 256 + wave * 64 + lane;
            int row = chunk >> 2, c8 = chunk & 3;
            gload16(Wb + (size_t)(768 + row) * 256 + k0 + c8 * 8,
                    &Bs[0][0] + (size_t)(j * 256 + wave * 64) * 8);
        }
        __syncthreads();
        int ar = wave * 16 + c0;
        s8v af = *(const s8v*)&As[ar][g * 8];
#pragma unroll
        for (int nt = 0; nt < 16; ++nt) {
            int r = nt * 16 + c0;
            s8v bfv = *(const s8v*)&Bs[r][g * 8];
            acc[nt] = __builtin_amdgcn_mfma_f32_16x16x32_bf16(af, bfv, acc[nt], 0, 0, 0);
        }
        __syncthreads();
    }
    int srow0 = mb * 64 + wave * 16 + g * 4;
    float sum[4] = {0, 0, 0, 0}, ssq[4] = {0, 0, 0, 0};
#pragma unroll
    for (int nt = 0; nt < 16; ++nt) {
        int col = nt * 16 + c0;
        float bov = bo[col];
#pragma unroll
        for (int r = 0; r < 4; ++r) {
            size_t node = (size_t)p * CORE_ + srow0 + r;
            float v = acc[nt][r] + bov + x[node * HH + col];
            acc[nt][r] = v;
            sum[r] += v; ssq[r] += v * v;
        }
    }
#pragma unroll
    for (int off = 1; off < 16; off <<= 1) {
#pragma unroll
        for (int r = 0; r < 4; ++r) {
            sum[r] += __shfl_xor(sum[r], off, 64);
            ssq[r] += __shfl_xor(ssq[r], off, 64);
        }
    }
#pragma unroll
    for (int r = 0; r < 4; ++r) {
        float mu = sum[r] * (1.f / HH);
        float var = ssq[r] * (1.f / HH) - mu * mu;
        float rstd = rsqrtf(var + 1e-5f);
        size_t node = (size_t)p * CORE_ + srow0 + r;
#pragma unroll
        for (int nt = 0; nt < 16; ++nt) {
            int col = nt * 16 + c0;
            out[node * HH + col] = (acc[nt][r] - mu) * rstd * ln_g[col] + ln_b[col];
        }
    }
}

extern "C" void kernel_launch(void* const* d_in, const int* in_sizes, int n_in,
                              void* d_out, int out_size, void* d_ws, size_t ws_size,
                              hipStream_t stream) {
    const float* x   = (const float*)d_in[0];
    const int* pidx  = (const int*)d_in[1];
    const float* Wq  = (const float*)d_in[3];
    const float* bq  = (const float*)d_in[4];
    const float* Wk  = (const float*)d_in[5];
    const float* bk  = (const float*)d_in[6];
    const float* Wv  = (const float*)d_in[7];
    const float* bv  = (const float*)d_in[8];
    const float* Wo  = (const float*)d_in[9];
    const float* bo  = (const float*)d_in[10];
    const float* lng = (const float*)d_in[11];
    const float* lnb = (const float*)d_in[12];

    // ws: qkv bf16 [P][S][768] (100.7MB) | att bf16 [P][192][256] (25.2MB)
    //     | Wb bf16 [1024][256] (0.5MB) | bb f32 [768]
    unsigned short* qkv = (unsigned short*)d_ws;
    unsigned short* att = qkv + (size_t)PP * SS * 768;
    unsigned short* Wb  = att + (size_t)PP * CORE_ * HH;
    float* bb = (float*)(Wb + 1024 * 256);

    k_prep<<<259, 256, 0, stream>>>(Wq, Wk, Wv, Wo, bq, bk, bv, Wb, bb);
    k_qkv<<<dim3(PP, 4, 3), 256, 0, stream>>>(x, pidx, Wb, bb, qkv);
    k_attn<<<dim3(PP, NHEAD), 256, 0, stream>>>(qkv, att);
    k_out<<<dim3(PP, 3), 256, 0, stream>>>(att, x, Wb, bo, lng, lnb, (float*)d_out);
}

// Round 6
// 159.316 us; speedup vs baseline: 1.0866x; 1.0474x over previous
//
#include <hip/hip_runtime.h>

#define PP 256
#define SS 256
#define CORE_ 192
#define HH 256
#define NHEAD 8
#define DD 32

typedef __attribute__((ext_vector_type(4))) float f32x4;
typedef __attribute__((ext_vector_type(8))) short s8v;
typedef __attribute__((ext_vector_type(4))) short s4v;

__device__ __forceinline__ float bf2f(unsigned short u) {
    union { unsigned int i; float f; } c; c.i = ((unsigned int)u) << 16; return c.f;
}
__device__ __forceinline__ unsigned short f2bf(float f) {
    union { float f; unsigned int i; } c; c.f = f;
    unsigned int i = c.i;
    return (unsigned short)((i + 0x7fffu + ((i >> 16) & 1u)) >> 16);
}

// async global->LDS 16B DMA; lds base must be wave-uniform (HW adds lane*16)
__device__ __forceinline__ void gload16(const unsigned short* g, unsigned short* l) {
    __builtin_amdgcn_global_load_lds(
        (const __attribute__((address_space(1))) void*)g,
        (__attribute__((address_space(3))) void*)l, 16, 0, 0);
}

// 16B-chunk XOR swizzle (involution) for [rows][32-short] tiles; 0-conflict (r3).
#define SW(row, chunk) ((chunk) ^ (((row) >> 1) & 3))
// store-side column swizzle within a 32-col window so that linear DMA + SW-read works
__device__ __forceinline__ int swcol(int c, int row) {
    return (c & ~31) | (((((c >> 3) & 3) ^ ((row >> 1) & 3))) << 3) | (c & 7);
}

// ---------------- K0: weight/bias pack (f32 -> bf16, pre-swizzled) -----
// blocks 0..127: Wb rows (Wq 0-255 | Wk 256-511 | Wv 512-767 | Wo 768-1023),
// one 8-short chunk per thread, source column SW-swizzled within 32-col window.
// blocks 128..130: bb[768] = {bq, bk, bv}
__global__ __launch_bounds__(256) void k_prep(
    const float* __restrict__ Wq, const float* __restrict__ Wk,
    const float* __restrict__ Wv, const float* __restrict__ Wo,
    const float* __restrict__ bq, const float* __restrict__ bk,
    const float* __restrict__ bv,
    unsigned short* __restrict__ Wb, float* __restrict__ bb) {
    int bid = blockIdx.x, tid = threadIdx.x;
    if (bid >= 128) {
        int which = bid - 128;
        const float* b = which == 0 ? bq : which == 1 ? bk : bv;
        bb[which * 256 + tid] = b[tid];
        return;
    }
    int c = bid * 256 + tid;   // chunk 0..32767
    int row = c >> 5;          // 0..1023
    int within = c & 31;
    int w = within >> 2, sl = within & 3;
    const float* src = row < 256 ? Wq : row < 512 ? Wk : row < 768 ? Wv : Wo;
    const float* sp = src + (size_t)(row & 255) * 256 + w * 32 + SW(row, sl) * 8;
    float4 a = *(const float4*)sp;
    float4 b4 = *(const float4*)(sp + 4);
    s8v wv;
    wv[0] = (short)f2bf(a.x); wv[1] = (short)f2bf(a.y);
    wv[2] = (short)f2bf(a.z); wv[3] = (short)f2bf(a.w);
    wv[4] = (short)f2bf(b4.x); wv[5] = (short)f2bf(b4.y);
    wv[6] = (short)f2bf(b4.z); wv[7] = (short)f2bf(b4.w);
    *(s8v*)(Wb + (size_t)row * 256 + w * 32 + sl * 8) = wv;
}

// ---------------- K1: QKV projection (2-phase pipelined) ---------------
// grid (P, 4 mt of 64 rows, 3 {Q,K,V}), block 256 (4 waves).
// Double-buffered As/Bs; STAGE(k+1) issued before compute(k); 1 barrier/step.
__global__ __launch_bounds__(256) void k_qkv(
    const float* __restrict__ x, const int* __restrict__ pidx,
    const unsigned short* __restrict__ Wb, const float* __restrict__ bb,
    unsigned short* __restrict__ qkv) {
    int p = blockIdx.x, mt = blockIdx.y, ng = blockIdx.z;
    if (ng == 0 && mt == 3) return;  // Q rows 192..255 never consumed
    __shared__ unsigned short As[2][64][32];
    __shared__ unsigned short Bs[2][256][32];
    int tid = threadIdx.x;
    int wave = tid >> 6, lane = tid & 63;
    int g = lane >> 4, c0 = lane & 15;
    f32x4 acc[4][4] = {};
    int arow = tid >> 2, aseg = tid & 3;
    int node = pidx[p * SS + mt * 64 + arow];
    const float* asrc = x + (size_t)node * HH + aseg * 8;
    const unsigned short* wsrc = Wb + (size_t)ng * 256 * 256;

    auto stage = [&](int k0, int b) {
        // B: 1024 x 16B chunks, async DMA from pre-swizzled Wb (linear LDS)
#pragma unroll
        for (int j = 0; j < 4; ++j) {
            int chunk = j * 256 + wave * 64 + lane;
            int row = chunk >> 2, c8 = chunk & 3;
            gload16(wsrc + (size_t)row * 256 + k0 + c8 * 8,
                    &Bs[b][0][0] + (size_t)(j * 256 + wave * 64) * 8);
        }
        // A: gathered x rows -> bf16, SW-swizzled reg stage
        float4 v0 = *(const float4*)(asrc + k0);
        float4 v1 = *(const float4*)(asrc + k0 + 4);
        s8v aw;
        aw[0] = (short)f2bf(v0.x); aw[1] = (short)f2bf(v0.y);
        aw[2] = (short)f2bf(v0.z); aw[3] = (short)f2bf(v0.w);
        aw[4] = (short)f2bf(v1.x); aw[5] = (short)f2bf(v1.y);
        aw[6] = (short)f2bf(v1.z); aw[7] = (short)f2bf(v1.w);
        *(s8v*)&As[b][arow][SW(arow, aseg) * 8] = aw;
    };

    stage(0, 0);
    __syncthreads();
#pragma unroll
    for (int ks = 0; ks < 8; ++ks) {
        int b = ks & 1;
        if (ks < 7) stage((ks + 1) * 32, b ^ 1);
        s8v af[4], bfv[4];
#pragma unroll
        for (int m2 = 0; m2 < 4; ++m2) {
            int r = m2 * 16 + c0;
            af[m2] = *(const s8v*)&As[b][r][SW(r, g) * 8];
        }
#pragma unroll
        for (int nt = 0; nt < 4; ++nt) {
            int r = wave * 64 + nt * 16 + c0;
            bfv[nt] = *(const s8v*)&Bs[b][r][SW(r, g) * 8];
        }
#pragma unroll
        for (int m2 = 0; m2 < 4; ++m2)
#pragma unroll
            for (int nt = 0; nt < 4; ++nt)
                acc[m2][nt] = __builtin_amdgcn_mfma_f32_16x16x32_bf16(
                    af[m2], bfv[nt], acc[m2][nt], 0, 0, 0);
        __syncthreads();
    }
    // epilogue: +bias; K-section (ng==1) stored column-swizzled for k_attn's DMA
#pragma unroll
    for (int nt = 0; nt < 4; ++nt) {
        int ncol = wave * 64 + nt * 16 + c0;
        float bv_ = bb[ng * 256 + ncol];
#pragma unroll
        for (int m2 = 0; m2 < 4; ++m2)
#pragma unroll
            for (int r = 0; r < 4; ++r) {
                int srow = mt * 64 + m2 * 16 + g * 4 + r;
                int sc = (ng == 1) ? swcol(ncol, srow) : ncol;
                qkv[((size_t)p * SS + srow) * 768 + ng * 256 + sc] =
                    f2bf(acc[m2][nt][r] + bv_);
            }
    }
}

// ---------------- K2: attention (MFMA) ---------------------------------
// grid (P, HEADS), block 256 = 4 waves; wave w handles mtiles w*3..w*3+2.
// K DMA'd (source pre-swizzled by k_qkv -> SW frag reads, 0-conflict);
// V reg-staged transposed; att stored column-swizzled for k_out's DMA.
__global__ __launch_bounds__(256) void k_attn(
    const unsigned short* __restrict__ qkv, unsigned short* __restrict__ att) {
    int p = blockIdx.x, h = blockIdx.y;
    __shared__ unsigned short Ks[256][32];
    __shared__ unsigned short Vt[32][256];
    __shared__ unsigned short Pb[4][16][256];
    int tid = threadIdx.x;
    int wave = tid >> 6, lane = tid & 63;
    int g = lane >> 4, c0 = lane & 15;

    // ---- stage K (DMA, linear dest; source pre-swizzled) ----
#pragma unroll
    for (int j = 0; j < 4; ++j) {
        int chunk = j * 256 + wave * 64 + lane;
        int row = chunk >> 2, c8 = chunk & 3;
        gload16(qkv + ((size_t)p * SS + row) * 768 + 256 + h * DD + c8 * 8,
                &Ks[0][0] + (size_t)(j * 256 + wave * 64) * 8);
    }
    // ---- stage V transposed (reg), swizzled ----
    {
        int chunk = tid & 3, rb = tid >> 2;
#pragma unroll
        for (int pass = 0; pass < 4; ++pass) {
            int row = rb + pass * 64;
            s8v vv = *(const s8v*)(qkv + ((size_t)p * SS + row) * 768 + 512 + h * DD + chunk * 8);
            int cj = row >> 3, jo = row & 7;
#pragma unroll
            for (int e = 0; e < 8; ++e) {
                int d = chunk * 8 + e;
                Vt[d][((cj ^ ((d >> 1) & 7)) << 3) + jo] = (unsigned short)vv[e];
            }
        }
    }
    __syncthreads();

    const float scale = 0.17677669529663687f;  // 1/sqrt(32)
    int cs = (c0 >> 1) & 7;

    for (int mi = 0; mi < 3; ++mi) {
        int q0 = (wave * 3 + mi) * 16;
        s8v qa = *(const s8v*)(qkv + ((size_t)p * SS + q0 + c0) * 768 + h * DD + g * 8);
        f32x4 sacc[16];
#pragma unroll
        for (int jt = 0; jt < 16; ++jt) {
            int row = jt * 16 + c0;
            s8v kf = *(const s8v*)&Ks[row][SW(row, g) * 8];
            sacc[jt] = __builtin_amdgcn_mfma_f32_16x16x32_bf16(
                qa, kf, f32x4{0.f, 0.f, 0.f, 0.f}, 0, 0, 0);
        }
        float linv[4];
#pragma unroll
        for (int r = 0; r < 4; ++r) {
            float mx = sacc[0][r];
#pragma unroll
            for (int jt = 1; jt < 16; ++jt) mx = fmaxf(mx, sacc[jt][r]);
#pragma unroll
            for (int off = 1; off < 16; off <<= 1)
                mx = fmaxf(mx, __shfl_xor(mx, off, 64));
            float sum = 0.f;
#pragma unroll
            for (int jt = 0; jt < 16; ++jt) {
                float e = __expf((sacc[jt][r] - mx) * scale);
                sacc[jt][r] = e;
                sum += e;
            }
#pragma unroll
            for (int off = 1; off < 16; off <<= 1)
                sum += __shfl_xor(sum, off, 64);
            linv[r] = 1.f / sum;
            int qq = g * 4 + r;
            int qs = (qq >> 1) & 7;
            unsigned short* prow = &Pb[wave][qq][0];
#pragma unroll
            for (int jt = 0; jt < 16; ++jt) {
                int j0 = jt * 2 + (c0 >> 3);
                prow[((j0 ^ qs) << 3) + (c0 & 7)] = (unsigned short)f2bf(sacc[jt][r]);
            }
        }
        asm volatile("s_waitcnt lgkmcnt(0)" ::: "memory");
        __builtin_amdgcn_sched_barrier(0);
        f32x4 oacc[2] = {f32x4{0.f, 0.f, 0.f, 0.f}, f32x4{0.f, 0.f, 0.f, 0.f}};
#pragma unroll
        for (int kt = 0; kt < 8; ++kt) {
            s8v pa = *(const s8v*)&Pb[wave][c0][(((kt * 4 + g) ^ cs) << 3)];
#pragma unroll
            for (int nt = 0; nt < 2; ++nt) {
                int d = nt * 16 + c0;
                s8v vb = *(const s8v*)&Vt[d][(((kt * 4 + g) ^ ((d >> 1) & 7)) << 3)];
                oacc[nt] = __builtin_amdgcn_mfma_f32_16x16x32_bf16(
                    pa, vb, oacc[nt], 0, 0, 0);
            }
        }
        asm volatile("s_waitcnt lgkmcnt(0)" ::: "memory");
        __builtin_amdgcn_sched_barrier(0);
#pragma unroll
        for (int nt = 0; nt < 2; ++nt)
#pragma unroll
            for (int r = 0; r < 4; ++r) {
                int qq = g * 4 + r;
                int crow = q0 + qq;
                int c = h * DD + nt * 16 + c0;
                att[((size_t)p * CORE_ + crow) * HH + swcol(c, crow)] =
                    f2bf(oacc[nt][r] * linv[r]);
            }
    }
}

// ---------------- K3: out-proj + residual + LayerNorm ------------------
// 2-phase pipelined; A (att) and B (Wo) DMA'd from pre-swizzled sources.
__global__ __launch_bounds__(256) void k_out(
    const unsigned short* __restrict__ att, const float* __restrict__ x,
    const unsigned short* __restrict__ Wb, const float* __restrict__ bo,
    const float* __restrict__ ln_g, const float* __restrict__ ln_b,
    float* __restrict__ out) {
    int p = blockIdx.x, mb = blockIdx.y;
    __shared__ unsigned short As[2][64][32];
    __shared__ unsigned short Bs[2][256][32];
    int tid = threadIdx.x;
    int wave = tid >> 6, lane = tid & 63;
    int g = lane >> 4, c0 = lane & 15;
    f32x4 acc[16] = {};

    auto stage = [&](int k0, int b) {
        {
            int chunk = wave * 64 + lane;
            int row = chunk >> 2, c8 = chunk & 3;
            gload16(att + ((size_t)p * CORE_ + mb * 64 + row) * HH + k0 + c8 * 8,
                    &As[b][0][0] + (size_t)(wave * 64) * 8);
        }
#pragma unroll
        for (int j = 0; j < 4; ++j) {
            int chunk = j * 256 + wave * 64 + lane;
            int row = chunk >> 2, c8 = chunk & 3;
            gload16(Wb + (size_t)(768 + row) * 256 + k0 + c8 * 8,
                    &Bs[b][0][0] + (size_t)(j * 256 + wave * 64) * 8);
        }
    };

    stage(0, 0);
    __syncthreads();
#pragma unroll
    for (int ks = 0; ks < 8; ++ks) {
        int b = ks & 1;
        if (ks < 7) stage((ks + 1) * 32, b ^ 1);
        int ar = wave * 16 + c0;
        s8v af = *(const s8v*)&As[b][ar][SW(ar, g) * 8];
#pragma unroll
        for (int nt = 0; nt < 16; ++nt) {
            int r = nt * 16 + c0;
            s8v bfv = *(const s8v*)&Bs[b][r][SW(r, g) * 8];
            acc[nt] = __builtin_amdgcn_mfma_f32_16x16x32_bf16(af, bfv, acc[nt], 0, 0, 0);
        }
        __syncthreads();
    }
    int srow0 = mb * 64 + wave * 16 + g * 4;
    float sum[4] = {0, 0, 0, 0}, ssq[4] = {0, 0, 0, 0};
#pragma unroll
    for (int nt = 0; nt < 16; ++nt) {
        int col = nt * 16 + c0;
        float bov = bo[col];
#pragma unroll
        for (int r = 0; r < 4; ++r) {
            size_t node = (size_t)p * CORE_ + srow0 + r;
            float v = acc[nt][r] + bov + x[node * HH + col];
            acc[nt][r] = v;
            sum[r] += v; ssq[r] += v * v;
        }
    }
#pragma unroll
    for (int off = 1; off < 16; off <<= 1) {
#pragma unroll
        for (int r = 0; r < 4; ++r) {
            sum[r] += __shfl_xor(sum[r], off, 64);
            ssq[r] += __shfl_xor(ssq[r], off, 64);
        }
    }
#pragma unroll
    for (int r = 0; r < 4; ++r) {
        float mu = sum[r] * (1.f / HH);
        float var = ssq[r] * (1.f / HH) - mu * mu;
        float rstd = rsqrtf(var + 1e-5f);
        size_t node = (size_t)p * CORE_ + srow0 + r;
#pragma unroll
        for (int nt = 0; nt < 16; ++nt) {
            int col = nt * 16 + c0;
            out[node * HH + col] = (acc[nt][r] - mu) * rstd * ln_g[col] + ln_b[col];
        }
    }
}

extern "C" void kernel_launch(void* const* d_in, const int* in_sizes, int n_in,
                              void* d_out, int out_size, void* d_ws, size_t ws_size,
                              hipStream_t stream) {
    const float* x   = (const float*)d_in[0];
    const int* pidx  = (const int*)d_in[1];
    const float* Wq  = (const float*)d_in[3];
    const float* bq  = (const float*)d_in[4];
    const float* Wk  = (const float*)d_in[5];
    const float* bk  = (const float*)d_in[6];
    const float* Wv  = (const float*)d_in[7];
    const float* bv  = (const float*)d_in[8];
    const float* Wo  = (const float*)d_in[9];
    const float* bo  = (const float*)d_in[10];
    const float* lng = (const float*)d_in[11];
    const float* lnb = (const float*)d_in[12];

    // ws: qkv bf16 [P][S][768] (100.7MB) | att bf16 [P][192][256] (25.2MB)
    //     | Wb bf16 [1024][256] (0.5MB, pre-swizzled) | bb f32 [768]
    unsigned short* qkv = (unsigned short*)d_ws;
    unsigned short* att = qkv + (size_t)PP * SS * 768;
    unsigned short* Wb  = att + (size_t)PP * CORE_ * HH;
    float* bb = (float*)(Wb + 1024 * 256);

    k_prep<<<131, 256, 0, stream>>>(Wq, Wk, Wv, Wo, bq, bk, bv, Wb, bb);
    k_qkv<<<dim3(PP, 4, 3), 256, 0, stream>>>(x, pidx, Wb, bb, qkv);
    k_attn<<<dim3(PP, NHEAD), 256, 0, stream>>>(qkv, att);
    k_out<<<dim3(PP, 3), 256, 0, stream>>>(att, x, Wb, bo, lng, lnb, (float*)d_out);
}